// Round 1
// baseline (6281.800 us; speedup 1.0000x reference)
//
#include <hip/hip_runtime.h>

// ============================================================================
// 2-layer tanh RNN (B=128,S=512,IN=128,H=512) + linear head (C=1000) + logsoftmax
//
// Pipeline (all on `stream`):
//   proj0:  xp0[t][b][j] = bf16( x[b][t][:]·W_ih0[j][:] + b_ih0[j]+b_hh0[j] )   -> bufA
//   init :  zero h-exchange buffers + flags (ws is poisoned 0xAA each call)
//   rec0 :  persistent 32-WG kernel, W_hh0 in registers as MFMA A-frags;
//           writes h_t in place over xp0 (same thread, same address) -> bufA=hs0
//   proj1:  xp1 = hs0·W_ih1^T + biases -> bufB
//   init, rec1 (stores only h_{511} as fp32)
//   head :  logits + log_softmax -> d_out (fp32 [128][1000])
//
// ws layout: [0,64MB) bufA | [64,128MB) bufB | +0 hbuf 256KB | +256KB flags 1KB
//            | +263168 h_last 256KB   (total ~128.6 MB)
// ============================================================================

using short8  = __attribute__((ext_vector_type(8))) short;
using floatx4 = __attribute__((ext_vector_type(4))) float;

#define DEV static __device__ __forceinline__

DEV unsigned short f2bf(float f) {
    union { float f; unsigned u; } v; v.f = f;
    unsigned r = (v.u + 0x7fffu + ((v.u >> 16) & 1u)) >> 16;
    return (unsigned short)r;
}
DEV float bf2f(unsigned short h) {
    union { unsigned u; float f; } v; v.u = ((unsigned)h) << 16;
    return v.f;
}
DEV float tanh_fast(float x) {
    float ax = fabsf(x);
    ax = fminf(ax, 12.0f);
    float e = __expf(-2.0f * ax);        // in (0,1], no overflow
    float r = (1.0f - e) / (1.0f + e);
    return copysignf(r, x);
}

// ---------------------------------------------------------------------------
// proj: out[m=t*128+b][n] = bf16( A[m][:]·W[n][:] + b1[n]+b2[n] )
// MODE 0: A = x fp32, row m=(t,b) at x + (b*512+t)*128   (K=128)
// MODE 1: A = hs bf16, row-major [m][K]                  (K=512)
// Tile 128(M) x 64(N), 256 threads (4 waves), wave = 32 M-rows, 8 acc tiles.
// ---------------------------------------------------------------------------
template <int K, int MODE>
__global__ __launch_bounds__(256, 2) void proj_kernel(
    const void* __restrict__ Aptr, const float* __restrict__ W,
    const float* __restrict__ b1, const float* __restrict__ b2,
    unsigned short* __restrict__ out)
{
    constexpr int LDA = 40;                       // bf16 elems; 80B row stride
    __shared__ unsigned short As[128 * LDA];      // 10.2 KB
    __shared__ unsigned short Ws[64 * LDA];       // 5.1 KB

    const int tid  = threadIdx.x;
    const int lane = tid & 63, wave = tid >> 6;
    const int lm   = lane & 15, lq = lane >> 4;
    const int nbase = blockIdx.x * 64;
    const int mtile = blockIdx.y;
    const int mbase = mtile * 128;

    floatx4 acc[2][4] = {};

    const int ar = tid >> 1, ak = (tid & 1) * 16;   // A stage: row, k-offset
    const int wr = tid >> 2, wk = (tid & 3) * 8;    // W stage

    for (int k0 = 0; k0 < K; k0 += 32) {
        // ---- stage A tile [128 x 32] as bf16 ----
        if (MODE == 0) {
            const float* x   = (const float*)Aptr;
            const float* src = x + ((size_t)ar * 512 + mtile) * 128 + (k0 + ak);
            float4 f0 = *(const float4*)(src + 0);
            float4 f1 = *(const float4*)(src + 4);
            float4 f2 = *(const float4*)(src + 8);
            float4 f3 = *(const float4*)(src + 12);
            unsigned short* d = As + ar * LDA + ak;
            d[0]=f2bf(f0.x); d[1]=f2bf(f0.y); d[2]=f2bf(f0.z); d[3]=f2bf(f0.w);
            d[4]=f2bf(f1.x); d[5]=f2bf(f1.y); d[6]=f2bf(f1.z); d[7]=f2bf(f1.w);
            d[8]=f2bf(f2.x); d[9]=f2bf(f2.y); d[10]=f2bf(f2.z); d[11]=f2bf(f2.w);
            d[12]=f2bf(f3.x); d[13]=f2bf(f3.y); d[14]=f2bf(f3.z); d[15]=f2bf(f3.w);
        } else {
            const unsigned short* h =
                (const unsigned short*)Aptr + (size_t)(mbase + ar) * K + k0 + ak;
            short8 v0 = *(const short8*)(h);
            short8 v1 = *(const short8*)(h + 8);
            *(short8*)(As + ar * LDA + ak)     = v0;
            *(short8*)(As + ar * LDA + ak + 8) = v1;
        }
        // ---- stage W tile [64 x 32] as bf16 ----
        {
            const float* src = W + (size_t)(nbase + wr) * K + k0 + wk;
            float4 f0 = *(const float4*)(src);
            float4 f1 = *(const float4*)(src + 4);
            unsigned short* d = Ws + wr * LDA + wk;
            d[0]=f2bf(f0.x); d[1]=f2bf(f0.y); d[2]=f2bf(f0.z); d[3]=f2bf(f0.w);
            d[4]=f2bf(f1.x); d[5]=f2bf(f1.y); d[6]=f2bf(f1.z); d[7]=f2bf(f1.w);
        }
        __syncthreads();

        short8 af0 = *(const short8*)(As + (wave * 32 +  0 + lm) * LDA + lq * 8);
        short8 af1 = *(const short8*)(As + (wave * 32 + 16 + lm) * LDA + lq * 8);
        #pragma unroll
        for (int nt = 0; nt < 4; ++nt) {
            short8 bf = *(const short8*)(Ws + (nt * 16 + lm) * LDA + lq * 8);
            acc[0][nt] = __builtin_amdgcn_mfma_f32_16x16x32_bf16(af0, bf, acc[0][nt], 0, 0, 0);
            acc[1][nt] = __builtin_amdgcn_mfma_f32_16x16x32_bf16(af1, bf, acc[1][nt], 0, 0, 0);
        }
        __syncthreads();
    }

    // ---- epilogue: C row m (quad*4+r), col n (lane&15) ----
    #pragma unroll
    for (int nt = 0; nt < 4; ++nt) {
        const int n = nbase + nt * 16 + lm;
        const float bias = b1[n] + b2[n];
        #pragma unroll
        for (int mt = 0; mt < 2; ++mt) {
            const int mrow = mbase + wave * 32 + mt * 16 + lq * 4;
            #pragma unroll
            for (int r = 0; r < 4; ++r)
                out[(size_t)(mrow + r) * 512 + n] = f2bf(acc[mt][nt][r] + bias);
        }
    }
}

// ---------------------------------------------------------------------------
__global__ void init_kernel(unsigned int* p, int n)
{
    int i = blockIdx.x * 256 + threadIdx.x;
    if (i < n) p[i] = 0u;
}

// ---------------------------------------------------------------------------
// rec: persistent recurrence. 32 WGs = 8 batch-groups(16 b) x 4 H-slices(128 j).
// blockIdx: g = blk & 7 (XCD swizzle -> siblings likely share an XCD),
//           s = blk >> 3.
// WG = 4 waves; wave owns 32 j rows (2 MFMA m-tiles), all 16 b (n).
// W_hh slice lives in registers as A-frags (2 x 16 x short8 = 128 VGPR).
// h exchange: hbuf[g][parity][b(16)][k(512)] bf16, double buffered;
// sync: per-group monotone flag counter, release/acquire at AGENT scope.
// mode 0: store h_t to hs_out (may alias xp — same thread/addr, read-then-write)
// mode 1: store only t=511 as fp32 to h_last.
// ---------------------------------------------------------------------------
__global__ __launch_bounds__(256, 1) void rec_kernel(
    const float* __restrict__ Whh,
    const unsigned short* xp,            // [S][B][H] bf16 (NO restrict: aliases hs_out)
    unsigned short* hs_out,              // [S][B][H] bf16
    float* __restrict__ h_last,          // [B][H] fp32
    unsigned short* __restrict__ hbuf,   // [8][2][16][512] bf16
    unsigned int* __restrict__ flags,    // [8*32], 128B apart
    int mode)
{
    const int tid  = threadIdx.x;
    const int lane = tid & 63;
    const int wave = tid >> 6;
    const int g = blockIdx.x & 7;
    const int s = blockIdx.x >> 3;
    const int lm = lane & 15, lq = lane >> 4;
    const int j0 = s * 128 + wave * 32;      // this wave's j base (covers 32 j)
    const int bb = g * 16 + lm;              // this lane's batch column

    // ---- preload W_hh A-fragments (fp32 -> bf16), 128 VGPRs ----
    short8 afr[2][16];
    #pragma unroll
    for (int jt = 0; jt < 2; ++jt) {
        const float* wrow = Whh + (size_t)(j0 + jt * 16 + lm) * 512;
        #pragma unroll
        for (int kt = 0; kt < 16; ++kt) {
            const float* p = wrow + kt * 32 + lq * 8;
            float4 wa = *(const float4*)(p);
            float4 wb = *(const float4*)(p + 4);
            short8 f;
            f[0]=(short)f2bf(wa.x); f[1]=(short)f2bf(wa.y);
            f[2]=(short)f2bf(wa.z); f[3]=(short)f2bf(wa.w);
            f[4]=(short)f2bf(wb.x); f[5]=(short)f2bf(wb.y);
            f[6]=(short)f2bf(wb.z); f[7]=(short)f2bf(wb.w);
            afr[jt][kt] = f;
        }
    }

    unsigned short* hb  = hbuf + (size_t)g * (2 * 16 * 512);
    unsigned int*   flg = flags + g * 32;
    int alive = 1;                           // spin bail-out (avoid hard hang)

    for (int t = 0; t < 512; ++t) {
        const unsigned short* hr = hb + ((t + 1) & 1) * (16 * 512) + lm * 512; // h_{t-1}
        unsigned short*       hw = hb + (t & 1) * (16 * 512) + lm * 512;       // h_t

        // xp operands for the epilogue (issued early; independent of siblings)
        const size_t xrow = ((size_t)t * 128 + bb) * 512;
        ushort4 x0 = *(const ushort4*)(xp + xrow + j0 +  0 + lq * 4);
        ushort4 x1 = *(const ushort4*)(xp + xrow + j0 + 16 + lq * 4);

        floatx4 acc0 = {0.f, 0.f, 0.f, 0.f};
        floatx4 acc1 = {0.f, 0.f, 0.f, 0.f};
        #pragma unroll
        for (int kt = 0; kt < 16; ++kt) {
            short8 bfr = *(const short8*)(hr + kt * 32 + lq * 8);  // B: n=lane&15(b), k
            acc0 = __builtin_amdgcn_mfma_f32_16x16x32_bf16(afr[0][kt], bfr, acc0, 0, 0, 0);
            acc1 = __builtin_amdgcn_mfma_f32_16x16x32_bf16(afr[1][kt], bfr, acc1, 0, 0, 0);
        }

        // epilogue: rows j0 + jt*16 + lq*4 + r, col b = bb
        float q00 = tanh_fast(acc0[0] + bf2f(x0.x));
        float q01 = tanh_fast(acc0[1] + bf2f(x0.y));
        float q02 = tanh_fast(acc0[2] + bf2f(x0.z));
        float q03 = tanh_fast(acc0[3] + bf2f(x0.w));
        float q10 = tanh_fast(acc1[0] + bf2f(x1.x));
        float q11 = tanh_fast(acc1[1] + bf2f(x1.y));
        float q12 = tanh_fast(acc1[2] + bf2f(x1.z));
        float q13 = tanh_fast(acc1[3] + bf2f(x1.w));

        ushort4 p0, p1;
        p0.x = f2bf(q00); p0.y = f2bf(q01); p0.z = f2bf(q02); p0.w = f2bf(q03);
        p1.x = f2bf(q10); p1.y = f2bf(q11); p1.z = f2bf(q12); p1.w = f2bf(q13);

        *(ushort4*)(hw + j0 +  0 + lq * 4) = p0;
        *(ushort4*)(hw + j0 + 16 + lq * 4) = p1;

        if (mode == 0) {
            *(ushort4*)(hs_out + xrow + j0 +  0 + lq * 4) = p0;
            *(ushort4*)(hs_out + xrow + j0 + 16 + lq * 4) = p1;
        } else if (t == 511) {
            float4 o0; o0.x = q00; o0.y = q01; o0.z = q02; o0.w = q03;
            float4 o1; o1.x = q10; o1.y = q11; o1.z = q12; o1.w = q13;
            *(float4*)(h_last + (size_t)bb * 512 + j0 +  0 + lq * 4) = o0;
            *(float4*)(h_last + (size_t)bb * 512 + j0 + 16 + lq * 4) = o1;
        }

        // ---- sibling sync: all stores drained at barrier (compiler emits
        // vmcnt(0) before s_barrier); one release-add flushes XCD L2; each
        // wave's lane0 acquire-spins (invalidates L1/L2 before re-reading h).
        __syncthreads();
        if (tid == 0)
            __hip_atomic_fetch_add(flg, 1u, __ATOMIC_RELEASE, __HIP_MEMORY_SCOPE_AGENT);
        if (lane == 0 && alive) {
            const unsigned tgt = 4u * (unsigned)(t + 1);
            int iters = 0;
            while (__hip_atomic_load(flg, __ATOMIC_ACQUIRE, __HIP_MEMORY_SCOPE_AGENT) < tgt) {
                if (++iters > 2000000) { alive = 0; break; }
            }
        }
        __syncthreads();
    }
}

// ---------------------------------------------------------------------------
// head: logits[b][c] = h_last[b][:]·W_out[c][:] + b_out[c]; log_softmax rows.
// One WG (256 thr) per batch row.
// ---------------------------------------------------------------------------
__global__ __launch_bounds__(256, 2) void head_kernel(
    const float* __restrict__ hl, const float* __restrict__ Wout,
    const float* __restrict__ bout, float* __restrict__ out)
{
    __shared__ float hrow[512];
    __shared__ float lg[1000];
    __shared__ float red[8];
    const int b = blockIdx.x, tid = threadIdx.x;

    hrow[tid]       = hl[(size_t)b * 512 + tid];
    hrow[tid + 256] = hl[(size_t)b * 512 + 256 + tid];
    __syncthreads();

    float lmax = -1e30f;
    for (int c = tid; c < 1000; c += 256) {
        const float4* w4 = (const float4*)(Wout + (size_t)c * 512);
        float a0 = 0.f, a1 = 0.f, a2 = 0.f, a3 = 0.f;
        #pragma unroll 4
        for (int k = 0; k < 128; ++k) {
            float4 w = w4[k];
            a0 += hrow[4 * k + 0] * w.x;
            a1 += hrow[4 * k + 1] * w.y;
            a2 += hrow[4 * k + 2] * w.z;
            a3 += hrow[4 * k + 3] * w.w;
        }
        float acc = bout[c] + (a0 + a1) + (a2 + a3);
        lg[c] = acc;
        lmax = fmaxf(lmax, acc);
    }
    // block max
    #pragma unroll
    for (int off = 32; off; off >>= 1) lmax = fmaxf(lmax, __shfl_down(lmax, off, 64));
    if ((tid & 63) == 0) red[tid >> 6] = lmax;
    __syncthreads();
    if (tid == 0) red[4] = fmaxf(fmaxf(red[0], red[1]), fmaxf(red[2], red[3]));
    __syncthreads();
    const float M = red[4];

    float lsum = 0.f;
    for (int c = tid; c < 1000; c += 256) lsum += __expf(lg[c] - M);
    #pragma unroll
    for (int off = 32; off; off >>= 1) lsum += __shfl_down(lsum, off, 64);
    __syncthreads();
    if ((tid & 63) == 0) red[tid >> 6] = lsum;
    __syncthreads();
    if (tid == 0) red[5] = M + __logf(red[0] + red[1] + red[2] + red[3]);
    __syncthreads();
    const float lse = red[5];

    for (int c = tid; c < 1000; c += 256)
        out[(size_t)b * 1000 + c] = lg[c] - lse;
}

// ---------------------------------------------------------------------------
extern "C" void kernel_launch(void* const* d_in, const int* in_sizes, int n_in,
                              void* d_out, int out_size, void* d_ws, size_t ws_size,
                              hipStream_t stream)
{
    const float* x    = (const float*)d_in[0];
    const float* Wih0 = (const float*)d_in[1];
    const float* Whh0 = (const float*)d_in[2];
    const float* bih0 = (const float*)d_in[3];
    const float* bhh0 = (const float*)d_in[4];
    const float* Wih1 = (const float*)d_in[5];
    const float* Whh1 = (const float*)d_in[6];
    const float* bih1 = (const float*)d_in[7];
    const float* bhh1 = (const float*)d_in[8];
    const float* Wout = (const float*)d_in[9];
    const float* bout = (const float*)d_in[10];
    float* out = (float*)d_out;

    char* ws = (char*)d_ws;
    unsigned short* bufA = (unsigned short*)ws;                            // 64 MB
    unsigned short* bufB = (unsigned short*)(ws + (size_t)64 * 1024 * 1024);
    char* aux            = ws + (size_t)128 * 1024 * 1024;
    unsigned short* hbuf = (unsigned short*)aux;                           // 262144 B
    unsigned int*  flags = (unsigned int*)(aux + 262144);                  // 1024 B
    float*         hlast = (float*)(aux + 263168);                         // 262144 B

    const dim3 pgrid(8, 512);

    proj_kernel<128, 0><<<pgrid, 256, 0, stream>>>((const void*)x, Wih0, bih0, bhh0, bufA);
    init_kernel<<<257, 256, 0, stream>>>((unsigned int*)hbuf, 65792);
    rec_kernel<<<32, 256, 0, stream>>>(Whh0, bufA, bufA, hlast, hbuf, flags, 0);

    proj_kernel<512, 1><<<pgrid, 256, 0, stream>>>((const void*)bufA, Wih1, bih1, bhh1, bufB);
    init_kernel<<<257, 256, 0, stream>>>((unsigned int*)hbuf, 65792);
    rec_kernel<<<32, 256, 0, stream>>>(Whh1, bufB, bufB, hlast, hbuf, flags, 1);

    head_kernel<<<128, 256, 0, stream>>>(hlast, Wout, bout, out);
}